// Round 2
// baseline (23742.064 us; speedup 1.0000x reference)
//
#include <hip/hip_runtime.h>
#include <cstdint>
#include <cstddef>

#define TT 512
#define BB 128
#define IN_DIM 128
#define HH 512
#define OO 64

#define DECAY  0.8187307530779818f
#define NSCALE 0.2870887f

typedef unsigned short u16;
typedef float f32x4 __attribute__((ext_vector_type(4)));
typedef short bf8 __attribute__((ext_vector_type(8)));

__device__ __forceinline__ u16 f2bf(float f) {
  union { float f; uint32_t u; } v; v.f = f;
  uint32_t r = v.u + 0x7FFFu + ((v.u >> 16) & 1u);
  return (u16)(r >> 16);
}
__device__ __forceinline__ float bf2f(u16 u) {
  union { uint32_t u; float f; } v; v.u = (uint32_t)u << 16;
  return v.f;
}
__device__ __forceinline__ f32x4 mfma16(bf8 a, bf8 b, f32x4 c) {
  return __builtin_amdgcn_mfma_f32_16x16x32_bf16(a, b, c, 0, 0, 0);
}

// ---------------------------------------------------------------------------
// Weight prep (unchanged from round 1): f32 weights -> bf16 MFMA B-fragments.
// WAF/WBF: [32 js][36 kb][512]  (kb 0..3 x-term, 4..19 h1-term, 20..35 h2-term)
// WOF:     [8 js][16 kb][512]
// ---------------------------------------------------------------------------
__global__ void wprep_kernel(
    const float* __restrict__ win1, const float* __restrict__ win2,
    const float* __restrict__ w11,  const float* __restrict__ w12,
    const float* __restrict__ w21,  const float* __restrict__ w22,
    const float* __restrict__ wdm,  const float* __restrict__ wem,
    u16* __restrict__ waf, u16* __restrict__ wbf, u16* __restrict__ wof) {
  size_t idx = (size_t)blockIdx.x * 256 + threadIdx.x;
  const size_t NWA = 32u * 36u * 512u;
  if (idx < 2 * NWA) {
    int isB = idx >= NWA;
    size_t i = isB ? (idx - NWA) : idx;
    int js  = (int)(i / (36 * 512));
    int rem = (int)(i % (36 * 512));
    int kb  = rem / 512;
    int li  = rem % 512;
    int lane = li >> 3, e = li & 7;
    int j    = js * 16 + (lane & 15);
    int koff = ((lane >> 4) << 3) + e;
    float val;
    if (kb < 4) {
      int k = kb * 32 + koff;
      val = (isB ? win2 : win1)[(size_t)k * HH + j];
    } else if (kb < 20) {
      int k = (kb - 4) * 32 + koff;
      val = (isB ? w12 : w11)[(size_t)k * HH + j];
    } else {
      int k = (kb - 20) * 32 + koff;
      val = (isB ? w22 : w21)[(size_t)k * HH + j];
    }
    (isB ? wbf : waf)[i] = f2bf(val);
  } else if (idx < 2 * NWA + 8u * 16u * 512u) {
    size_t i = idx - 2 * NWA;
    int js  = (int)(i / (16 * 512));
    int rem = (int)(i % (16 * 512));
    int kb  = rem / 512;
    int li  = rem % 512;
    int lane = li >> 3, e = li & 7;
    int j = js * 16 + (lane & 15);
    int k = kb * 32 + ((lane >> 4) << 3) + e;
    float val = (j < 64) ? wdm[(size_t)k * OO + j] : wem[(size_t)k * OO + (j - 64)];
    wof[i] = f2bf(val);
  }
}

// ---------------------------------------------------------------------------
// Persistent scan kernel.
// 8 groups (16 batch rows each, independent recurrences). Group = 16 WGs x 256
// thr = 64 waves: waves 0..31 compute h1 (phase A), 32..63 compute h2 (phase B).
// Wave nt owns output cols [16nt,16nt+16): 36 weight B-fragments in 144 VGPRs,
// OU-noise + h-master state in 8 VGPRs. Shared state = bf16 h mirrors [16][512],
// double-buffered by t-parity, exchanged via agent-scope release/acquire.
// Handshake: A(t) waits flagB >= 32t; B(t) waits flagA >= 32(t+1).
// x/eps loads issued BEFORE the spin (state-independent) to hide HBM latency.
// ---------------------------------------------------------------------------
__global__ __launch_bounds__(256, 1) void scan_kernel(
    const float* __restrict__ x1,   const float* __restrict__ x2,
    const float* __restrict__ eps1, const float* __restrict__ eps2,
    const u16* __restrict__ waf, const u16* __restrict__ wbf,
    u16* mir, int* flags, u16* __restrict__ hs) {
  int g      = blockIdx.x & 7;        // round-robin dispatch -> same XCD (heuristic)
  int member = blockIdx.x >> 3;
  int wid    = member * 4 + (threadIdx.x >> 6);
  int l      = threadIdx.x & 63;
  int phase  = wid >> 5;              // 0 = h1 (A), 1 = h2 (B)
  int nt     = wid & 31;

  // weights resident in VGPRs for the whole scan
  const u16* wbase = (phase ? wbf : waf) + (size_t)nt * (36 * 512);
  bf8 w[36];
#pragma unroll
  for (int kb = 0; kb < 36; ++kb)
    w[kb] = *(const bf8*)(wbase + kb * 512 + l * 8);

  u16* gm = mir + (size_t)g * 32768;  // h1[2][16][512] | h2[2][16][512], u16 units
  int* flagA = flags + g * 32;
  int* flagB = flagA + 1;

  const float* x   = phase ? x2 : x1;
  const float* eps = phase ? eps2 : eps1;

  int al    = l & 15;           // A-fragment row (group-local)
  int kgrp  = (l >> 4) * 8;     // k offset within 32-wide kb
  int row0  = (l >> 4) * 4;     // C-tile row base (group-local)
  int colg  = nt * 16 + al;     // output column
  int growA = g * 16 + al;      // global batch row for A-fragments
  int growC = g * 16 + row0;    // global batch row base for C rows

  float nreg[4] = {0.f, 0.f, 0.f, 0.f};
  float hreg[4] = {0.f, 0.f, 0.f, 0.f};

  for (int t = 0; t < TT; ++t) {
    // ---- prefetch x fragments + eps (independent of the handshake) ----
    const float* xp = x + ((size_t)t * BB + growA) * IN_DIM + kgrp;
    bf8 xa[4];
#pragma unroll
    for (int kb = 0; kb < 4; ++kb) {
      f32x4 lo = *(const f32x4*)(xp + kb * 32);
      f32x4 hi = *(const f32x4*)(xp + kb * 32 + 4);
      bf8 a;
#pragma unroll
      for (int e = 0; e < 4; ++e) {
        a[e]     = (short)f2bf(lo[e]);
        a[4 + e] = (short)f2bf(hi[e]);
      }
      xa[kb] = a;
    }
    float epsv[4];
#pragma unroll
    for (int r = 0; r < 4; ++r)
      epsv[r] = eps[((size_t)t * BB + growC + r) * HH + colg];

    // ---- wait for the producer half ----
    {
      int* fp  = phase ? flagA : flagB;
      int  tgt = phase ? 32 * (t + 1) : 32 * t;
      while (__hip_atomic_load(fp, __ATOMIC_RELAXED, __HIP_MEMORY_SCOPE_AGENT) < tgt)
        __builtin_amdgcn_s_sleep(1);
      __threadfence();  // acquire: invalidate caches before reading mirrors
    }

    int p = t & 1, q = p ^ 1;
    const u16* h1r = gm + (phase ? q : p) * 8192;  // A: h1(t-1)@p, B: h1(t)@q
    const u16* h2r = gm + 16384 + p * 8192;        // h2(t-1)@p
    u16* dst = phase ? (gm + 16384 + q * 8192) : (gm + q * 8192);

    // ---- K-loop: 36 MFMA over 4 independent accumulator chains ----
    f32x4 acc[4];
#pragma unroll
    for (int i = 0; i < 4; ++i) acc[i] = (f32x4){0.f, 0.f, 0.f, 0.f};
#pragma unroll
    for (int kb = 0; kb < 4; ++kb)
      acc[kb] = mfma16(xa[kb], w[kb], acc[kb]);
    const u16* h1p = h1r + al * 512 + kgrp;
#pragma unroll
    for (int kb = 4; kb < 20; ++kb) {
      bf8 a = *(const bf8*)(h1p + (kb - 4) * 32);
      acc[kb & 3] = mfma16(a, w[kb], acc[kb & 3]);
    }
    const u16* h2p = h2r + al * 512 + kgrp;
#pragma unroll
    for (int kb = 20; kb < 36; ++kb) {
      bf8 a = *(const bf8*)(h2p + (kb - 20) * 32);
      acc[kb & 3] = mfma16(a, w[kb], acc[kb & 3]);
    }
    f32x4 accs = (acc[0] + acc[1]) + (acc[2] + acc[3]);

    // ---- epilogue: OU noise, sigmoid, leak; state lives in registers ----
#pragma unroll
    for (int r = 0; r < 4; ++r) {
      nreg[r] = nreg[r] * DECAY + NSCALE * epsv[r];
      float pre = accs[r] + nreg[r];
      float s = 1.0f / (1.0f + __expf(-pre));
      hreg[r] = hreg[r] * 0.9f + 0.1f * s;
      dst[(row0 + r) * 512 + colg] = f2bf(hreg[r]);
    }
    if (phase) {
      const u16* h1n = gm + q * 8192;  // new h1(t)
#pragma unroll
      for (int r = 0; r < 4; ++r) {
        float h1v = bf2f(h1n[(row0 + r) * 512 + colg]);
        hs[((size_t)t * BB + growC + r) * HH + colg] = f2bf(h1v + hreg[r]);
      }
    }

    // ---- release + signal ----
    __threadfence();
    if (l == 0)
      __hip_atomic_fetch_add(phase ? flagB : flagA, 1,
                             __ATOMIC_RELEASE, __HIP_MEMORY_SCOPE_AGENT);
  }
}

// ---------------------------------------------------------------------------
// Output projection (unchanged from round 1): y = hsum @ Wout, f32 out.
// ---------------------------------------------------------------------------
__global__ __launch_bounds__(256) void outgemm_kernel(
    const u16* __restrict__ hs, const u16* __restrict__ wof,
    float* __restrict__ out) {
  int ng = blockIdx.x & 3;
  int mg = blockIdx.x >> 2;
  int tid = threadIdx.x;
  int w = tid >> 6, l = tid & 63;

  __shared__ u16 wlds[2 * 16 * 512];
  {
    const uint32_t* src = (const uint32_t*)(wof + (size_t)ng * (2 * 16 * 512));
    uint32_t* dst = (uint32_t*)wlds;
#pragma unroll
    for (int i = 0; i < 32; ++i) dst[tid + i * 256] = src[tid + i * 256];
  }
  __syncthreads();

  int mbase = mg * 64 + w * 16;
  int arow = mbase + (l & 15);
  int kgrp = (l >> 4) * 8;
  const u16* ap = hs + (size_t)arow * HH;

  f32x4 acc0 = {0.f, 0.f, 0.f, 0.f}, acc1 = {0.f, 0.f, 0.f, 0.f};
#pragma unroll
  for (int kb = 0; kb < 16; ++kb) {
    bf8 a  = *(const bf8*)(ap + kb * 32 + kgrp);
    bf8 b0 = *(const bf8*)(wlds + kb * 512 + l * 8);
    bf8 b1 = *(const bf8*)(wlds + 8192 + kb * 512 + l * 8);
    acc0 = mfma16(a, b0, acc0);
    acc1 = mfma16(a, b1, acc1);
  }

  int row0 = mbase + ((l >> 4) << 2);
  float* out_em = out + (size_t)TT * BB * OO;
#pragma unroll
  for (int q = 0; q < 2; ++q) {
    f32x4 acc = q ? acc1 : acc0;
    int jg = ng * 32 + q * 16 + (l & 15);
    float* base = (jg < 64) ? out : out_em;
    int col = jg & 63;
#pragma unroll
    for (int r = 0; r < 4; ++r)
      base[(size_t)(row0 + r) * OO + col] = acc[r];
  }
}

// ---------------------------------------------------------------------------
// Workspace layout (bytes):
//   0        MIR    8 groups x 65536  = 524288   (h1[2][16][512] | h2[2][16][512] bf16)
//   524288   FLAGS  8 x 128           = 1024     (flagA, flagB per group, padded)
//   1048576  WAF    1179648
//   2228224  WBF    1179648
//   3407872  WOF    131072
//   4194304  HS     67108864                     hsum [T][B][H] bf16
//   end 71303168 (same footprint as round 1)
// ---------------------------------------------------------------------------
extern "C" void kernel_launch(void* const* d_in, const int* in_sizes, int n_in,
                              void* d_out, int out_size, void* d_ws, size_t ws_size,
                              hipStream_t stream) {
  const float* x1   = (const float*)d_in[0];
  const float* x2   = (const float*)d_in[1];
  const float* eps1 = (const float*)d_in[2];
  const float* eps2 = (const float*)d_in[3];
  const float* win1 = (const float*)d_in[4];
  const float* win2 = (const float*)d_in[5];
  const float* w11  = (const float*)d_in[6];
  const float* w12  = (const float*)d_in[7];
  const float* w21  = (const float*)d_in[8];
  const float* w22  = (const float*)d_in[9];
  const float* wdm  = (const float*)d_in[10];
  const float* wem  = (const float*)d_in[11];

  char* ws = (char*)d_ws;
  u16*  MIR   = (u16*)(ws + 0);
  int*  FLAGS = (int*)(ws + 524288);
  u16*  WAF   = (u16*)(ws + 1048576);
  u16*  WBF   = (u16*)(ws + 2228224);
  u16*  WOF   = (u16*)(ws + 3407872);
  u16*  HS    = (u16*)(ws + 4194304);

  // zero mirrors (h(-1)=0) and handshake flags
  hipMemsetAsync(ws, 0, 525312, stream);

  wprep_kernel<<<4864, 256, 0, stream>>>(win1, win2, w11, w12, w21, w22,
                                         wdm, wem, WAF, WBF, WOF);

  scan_kernel<<<128, 256, 0, stream>>>(x1, x2, eps1, eps2, WAF, WBF,
                                       MIR, FLAGS, HS);

  outgemm_kernel<<<4096, 256, 0, stream>>>(HS, WOF, (float*)d_out);
}